// Round 7
// baseline (375.594 us; speedup 1.0000x reference)
//
#include <hip/hip_runtime.h>
#include <hip/hip_bf16.h>
#include <math.h>

// BinaryTreeLSTM — round 7: fully fused level kernels.
//
// Weight packing (gate-interleaved): packed row e' = (j/16)*64 + g*16 + (j%16)
//   for gate g, output col j; original W row = g*2048 + j.
//   Wcat[4096][3072] bf16 = [W_ih | W_hh] packed rows.
// Xcat: level-k A-slab at row OFF(k)=4096-2^(k+1), 2^k rows x 3072 bf16:
//   [0,1024) = bf16(emb[node]); [1024,3072) = h of children (written by the
//   epilogue of level k+1). Row stride 3072.
// c compact: level k writes c of even nodes only (row m>>1, 1024 f32);
//   level k-1 reads row m.
//
// fused_level<BM,WM,WN,KS>: 512 threads / 8 waves; BN=128 (= 32 j x 4 gates);
// waves: w = kg*(WM*WN) + wm*WN + wn. K-groups kg do disjoint K-chunks,
// LDS-reduced after the K-loop; wave tile 16 x (128/WN).
// In the MFMA C-layout a lane's n-frags 4b+{0,1,2,3} are gates i,f,g,o of
// column j = jblk*16 + (lane&15) -> LSTM cell fully in-register.

#define TREE_DEPTH 12
#define GCOLS 4096

typedef unsigned short u16;
typedef unsigned int u32;
typedef __attribute__((ext_vector_type(8))) short bf16x8;
typedef __attribute__((ext_vector_type(4))) float f32x4;

__device__ __forceinline__ void gload16(const void* g, void* l) {
    __builtin_amdgcn_global_load_lds(
        (const __attribute__((address_space(1))) u32*)g,
        (__attribute__((address_space(3))) u32*)l, 16, 0, 0);
}

__device__ __forceinline__ u16 f2bf(float f) {
    __hip_bfloat16 h = __float2bfloat16(f);
    return *reinterpret_cast<u16*>(&h);
}

// ---------------------------------------------------------------- converts
__global__ void bias_kernel(const float* __restrict__ b_ih,
                            const float* __restrict__ b_hh,
                            float* __restrict__ bg) {
    int idx = blockIdx.x * blockDim.x + threadIdx.x;   // 0..4095: g*1024+j
    int g = idx >> 10, j = idx & 1023;
    int r = g * 2048 + j;
    bg[idx] = b_ih[r] + b_hh[r];
}

// Pack W_ih|W_hh -> Wcat[4096][3072], gate-interleaved rows, XCD-affine
// write order: 128-row tile ct=e'>>7 is written by blocks with b&7 == ct%8.
__global__ void pack_w(const float* __restrict__ Wih,
                       const float* __restrict__ Whh,
                       u16* __restrict__ Wcat) {
    const int b = blockIdx.x;          // 0..4095
    const int seg = blockIdx.y;        // 0: ih, 1/2: hh halves
    const int x = b & 7, t = b >> 3;   // t in [0,512)
    const int e = ((t & 3) * 8 + x) * 128 + (t >> 2);  // (e>>7)%8 == x
    const int jhi = e >> 6, g = (e >> 4) & 3, jlo = e & 15;
    const int j = jhi * 16 + jlo;
    const int wr = g * 2048 + j;
    const int col = threadIdx.x * 4;   // 0..1020
    float4 v;
    if (seg == 0)
        v = *reinterpret_cast<const float4*>(Wih + (size_t)wr * 1024 + col);
    else
        v = *reinterpret_cast<const float4*>(Whh + (size_t)wr * 2048 + (seg - 1) * 1024 + col);
    uint2 p = make_uint2((u32)f2bf(v.x) | ((u32)f2bf(v.y) << 16),
                         (u32)f2bf(v.z) | ((u32)f2bf(v.w) << 16));
    *reinterpret_cast<uint2*>(Wcat + (size_t)e * 3072 + seg * 1024 + col) = p;
}

// Scatter emb rows into each level's Xcat slab (x-part).
__global__ void conv_emb_cat(const float* __restrict__ emb, u16* __restrict__ Xcat) {
    const int r = blockIdx.x;                 // 0..4094 (node id)
    const int k = 31 - __builtin_clz(r + 1);  // level
    const int m = (r + 1) - (1 << k);
    const size_t drow = (size_t)(4096 - (2 << k) + m);
    const int col = threadIdx.x * 4;
    float4 v = *reinterpret_cast<const float4*>(emb + (size_t)r * 1024 + col);
    uint2 p = make_uint2((u32)f2bf(v.x) | ((u32)f2bf(v.y) << 16),
                         (u32)f2bf(v.z) | ((u32)f2bf(v.w) << 16));
    *reinterpret_cast<uint2*>(Xcat + drow * 3072 + col) = p;
}

// ---------------------------------------------------------------- fused level
template <int BM, int WM, int WN, int KS>
__global__ __launch_bounds__(512) void fused_level(
    const u16* __restrict__ A,       // level slab: n rows x 3072 (stride 3072)
    const u16* __restrict__ Wc,      // Wcat 4096 x 3072
    const float* __restrict__ bg,    // 4096 (g*1024+j)
    const float* __restrict__ cprev, // compact c (1024-wide) or null
    u16* __restrict__ hnext,         // next slab h-region base (or null)
    float* __restrict__ cnext,       // compact c out
    float* __restrict__ outp,        // null unless n==1
    int n, int Ktot)
{
    constexpr int WMN = WM * WN;
    constexpr int NF  = 8 / WN;            // n-frags per wave
    __shared__ u16 As[KS * BM * 32];
    __shared__ u16 Bs[KS * 128 * 32];

    // stable XCD<->c-tile affinity: ct%8 == (linear block id)%8 at every level
    const int gx = gridDim.x;
    int b = blockIdx.x + gx * blockIdx.y;
    const int x = b & 7, t = b >> 3;
    const int ct = (t & 3) * 8 + x;        // 0..31
    const int mt = t >> 2;                 // 0..gx-1

    const int m0 = mt * BM;
    const int c0 = ct * 128;

    const int tid  = threadIdx.x;
    const int lane = tid & 63;
    const int w    = tid >> 6;
    const int kg   = w / WMN;
    const int wr_  = w % WMN;
    const int wm   = wr_ / WN;
    const int wn   = wr_ % WN;

    const int Kc   = Ktot / KS;
    const int kbeg = kg * Kc;
    const int tg   = wr_ * 64 + lane;      // thread index within K-group

    // A staging: slots [0, BM*4), one gload16 each (slot s: row s>>2, k (s&3)*8)
    const bool doA = (tg < BM * 4);
    int arow = m0 + (tg >> 2);
    if (arow > n - 1) arow = n - 1;
    const u16* pA = A + (size_t)arow * 3072 + kbeg + (tg & 3) * 8;
    u16* dstA = As + kg * BM * 32 + tg * 8;

    // B staging: 512 slots per group, KS per thread
    const u16* pB[KS];
    u16* dstB[KS];
    #pragma unroll
    for (int p = 0; p < KS; ++p) {
        const int s = tg + p * (WMN * 64);
        pB[p] = Wc + (size_t)(c0 + (s >> 2)) * 3072 + kbeg + (s & 3) * 8;
        dstB[p] = Bs + kg * 128 * 32 + s * 8;
    }

    f32x4 acc[NF];
    #pragma unroll
    for (int f = 0; f < NF; ++f) acc[f] = f32x4{0.f, 0.f, 0.f, 0.f};

    const int fl = lane & 15;
    const int kb = (lane >> 4) * 8;
    const u16* aRd = As + kg * BM * 32 + (wm * 16 + fl) * 32 + kb;
    const u16* bRd = Bs + kg * 128 * 32 + (wn * (NF * 16) + fl) * 32 + kb;

    for (int kk = 0; kk < Kc; kk += 32) {
        if (doA) { gload16(pA, dstA); pA += 32; }
        #pragma unroll
        for (int p = 0; p < KS; ++p) { gload16(pB[p], dstB[p]); pB[p] += 32; }
        __syncthreads();

        bf16x8 a = *reinterpret_cast<const bf16x8*>(aRd);
        #pragma unroll
        for (int f = 0; f < NF; ++f) {
            bf16x8 bb = *reinterpret_cast<const bf16x8*>(bRd + f * 16 * 32);
            acc[f] = __builtin_amdgcn_mfma_f32_16x16x32_bf16(a, bb, acc[f], 0, 0, 0);
        }
        __syncthreads();
    }

    // -------- cross-K-group reduction (reuse Bs as scratch)
    if constexpr (KS > 1) {
        f32x4* red = reinterpret_cast<f32x4*>(Bs);
        if (kg > 0) {
            #pragma unroll
            for (int f = 0; f < NF; ++f)
                red[(((kg - 1) * WMN + wr_) * NF + f) * 64 + lane] = acc[f];
        }
        __syncthreads();
        if (kg == 0) {
            #pragma unroll
            for (int q = 1; q < KS; ++q)
                #pragma unroll
                for (int f = 0; f < NF; ++f) {
                    f32x4 v = red[(((q - 1) * WMN + wr_) * NF + f) * 64 + lane];
                    acc[f][0] += v[0]; acc[f][1] += v[1];
                    acc[f][2] += v[2]; acc[f][3] += v[3];
                }
        }
    }

    // -------- LSTM cell epilogue (kg == 0 waves)
    if (kg != 0) return;
    #pragma unroll
    for (int jb = 0; jb < NF / 4; ++jb) {
        const int eb = c0 + wn * (NF * 16) + jb * 64;
        const int j = (eb >> 6) * 16 + fl;
        const float bi = bg[j], bf = bg[1024 + j];
        const float bgg = bg[2048 + j], bo = bg[3072 + j];
        const f32x4 iv = acc[jb * 4 + 0], fv = acc[jb * 4 + 1];
        const f32x4 gv = acc[jb * 4 + 2], ov = acc[jb * 4 + 3];
        #pragma unroll
        for (int r = 0; r < 4; ++r) {
            const int m = m0 + wm * 16 + (lane >> 4) * 4 + r;
            if (m >= n) continue;
            const float i_ = iv[r] + bi, f_ = fv[r] + bf;
            const float g_ = gv[r] + bgg, o_ = ov[r] + bo;
            const float cc = cprev ? cprev[(size_t)m * 1024 + j] : 0.f;
            const float si = 1.0f / (1.0f + expf(-i_));
            const float sf = 1.0f / (1.0f + expf(-f_));
            const float so = 1.0f / (1.0f + expf(-o_));
            const float cn = sf * cc + si * tanhf(g_);
            const float hn = so * tanhf(cn);
            if (hnext)
                hnext[(size_t)(m >> 1) * 3072 + (m & 1) * 1024 + j] = f2bf(hn);
            if (!(m & 1))
                cnext[(size_t)(m >> 1) * 1024 + j] = cn;
            if (outp) { outp[j] = hn; outp[1024 + j] = cn; }
        }
    }
}

// ---------------------------------------------------------------- launcher
extern "C" void kernel_launch(void* const* d_in, const int* in_sizes, int n_in,
                              void* d_out, int out_size, void* d_ws, size_t ws_size,
                              hipStream_t stream) {
    const float* emb  = (const float*)d_in[0];
    const float* W_ih = (const float*)d_in[1];
    const float* W_hh = (const float*)d_in[2];
    const float* b_ih = (const float*)d_in[3];
    const float* b_hh = (const float*)d_in[4];
    float* out = (float*)d_out;

    char* p = (char*)d_ws;
    float* bg  = (float*)p;  p += 16384;
    u16* Wcat  = (u16*)p;    p += (size_t)4096 * 3072 * 2;   // 25.2 MB
    u16* Xcat  = (u16*)p;    p += (size_t)4096 * 3072 * 2;   // 25.2 MB
    float* cbA = (float*)p;  p += (size_t)1024 * 1024 * 4;   //  4.2 MB
    float* cbB = (float*)p;  p += (size_t)1024 * 1024 * 4;   //  4.2 MB

    bias_kernel<<<16, 256, 0, stream>>>(b_ih, b_hh, bg);
    pack_w<<<dim3(4096, 3), 256, 0, stream>>>(W_ih, W_hh, Wcat);
    conv_emb_cat<<<4095, 256, 0, stream>>>(emb, Xcat);

    #define OFF(k) (4096 - (2 << (k)))

    // level 11: K=1024 (h=c=0), writes h into level-10 slab, c into cbA.
    fused_level<64, 4, 2, 1><<<dim3(32, 32), 512, 0, stream>>>(
        Xcat, Wcat, bg, nullptr,
        Xcat + (size_t)OFF(10) * 3072 + 1024, cbA, nullptr, 2048, 1024);

    const float* cprev = cbA;
    float* cbufs[2] = {cbB, cbA};
    int t = 0;
    for (int k = TREE_DEPTH - 2; k >= 0; --k) {
        const int n = 1 << k;
        const u16* A = Xcat + (size_t)OFF(k) * 3072;
        u16* hnext = (k > 0) ? (Xcat + (size_t)OFF(k - 1) * 3072 + 1024) : nullptr;
        float* cnext = cbufs[t];
        float* outp = (k == 0) ? out : nullptr;

        if (k >= 9) {          // n=1024/512: BM=64, full-K waves
            dim3 grid(n / 64, 32);
            fused_level<64, 4, 2, 1><<<grid, 512, 0, stream>>>(
                A, Wcat, bg, cprev, hnext, cnext, outp, n, 3072);
        } else if (k == 8) {   // n=256: BM=32, 2-way K-split
            dim3 grid(8, 32);
            fused_level<32, 2, 2, 2><<<grid, 512, 0, stream>>>(
                A, Wcat, bg, cprev, hnext, cnext, outp, n, 3072);
        } else {               // n<=128: BM=16, 4-way K-split
            dim3 grid((n + 15) / 16, 32);
            fused_level<16, 1, 2, 4><<<grid, 512, 0, stream>>>(
                A, Wcat, bg, cprev, hnext, cnext, outp, n, 3072);
        }
        cprev = cnext; t ^= 1;
    }
}

// Round 8
// 301.025 us; speedup vs baseline: 1.2477x; 1.2477x over previous
//
#include <hip/hip_runtime.h>
#include <hip/hip_bf16.h>
#include <math.h>

// BinaryTreeLSTM — round 8: fused level kernels, dense wave tiles,
// double-buffered LDS with counted vmcnt (T3/T4-min pipeline).
//
// Wcat[4096][3072] bf16, gate-interleaved packed row e = (j/16)*64 + g*16 +
//   (j%16) (orig W row g*2048+j); cols [0,1024)=W_ih, [1024,3072)=W_hh.
// Xcat slabs: level k at row OFF(k)=4096-2^(k+1), 2^k rows x 3072:
//   [0,1024)=bf16(emb[node]); [1024,3072)=children h (written by level k+1).
// c compact: level k writes even-node c at row m>>1 (1024 f32); k-1 reads row m.
//
// fused_level<MI,MW,NW,KG>: BM=MI*16*MW rows, BN=NW*64 cols, MW*NW*KG waves.
// KG groups take disjoint K-chunks (LDS-reduced at end). Wave tile =
// (MI*16) x 64: MI*4 MFMAs per BK=32 step. In the C-layout, n-frag f = gate f
// of column j=((c0+wn*64)>>6)*16 + (lane&15) -> in-register LSTM cell.

#define TREE_DEPTH 12

typedef unsigned short u16;
typedef unsigned int u32;
typedef __attribute__((ext_vector_type(8))) short bf16x8;
typedef __attribute__((ext_vector_type(4))) float f32x4;

__device__ __forceinline__ void gload16(const void* g, void* l) {
    __builtin_amdgcn_global_load_lds(
        (const __attribute__((address_space(1))) u32*)g,
        (__attribute__((address_space(3))) u32*)l, 16, 0, 0);
}

template <int N>
__device__ __forceinline__ void vmwait() {
    asm volatile("s_waitcnt vmcnt(%0)" :: "n"(N) : "memory");
}

__device__ __forceinline__ void barrier_pinned() {
    __builtin_amdgcn_sched_barrier(0);
    __builtin_amdgcn_s_barrier();
    __builtin_amdgcn_sched_barrier(0);
}

__device__ __forceinline__ u16 f2bf(float f) {
    __hip_bfloat16 h = __float2bfloat16(f);
    return *reinterpret_cast<u16*>(&h);
}

// ---------------------------------------------------------------- converts
__global__ void bias_kernel(const float* __restrict__ b_ih,
                            const float* __restrict__ b_hh,
                            float* __restrict__ bg) {
    int idx = blockIdx.x * blockDim.x + threadIdx.x;   // 0..4095: g*1024+j
    int g = idx >> 10, j = idx & 1023;
    int r = g * 2048 + j;
    bg[idx] = b_ih[r] + b_hh[r];
}

// Pack W_ih|W_hh -> Wcat[4096][3072], gate-interleaved rows; 128-row tile
// (e>>7) is written by blocks with b&7 == (e>>7)%8 (XCD affinity).
__global__ void pack_w(const float* __restrict__ Wih,
                       const float* __restrict__ Whh,
                       u16* __restrict__ Wcat) {
    const int b = blockIdx.x;          // 0..4095
    const int seg = blockIdx.y;        // 0: ih, 1/2: hh halves
    const int x = b & 7, t = b >> 3;   // t in [0,512)
    const int e = ((t & 3) * 8 + x) * 128 + (t >> 2);  // (e>>7)%8 == x
    const int g = (e >> 4) & 3;
    const int j = (e >> 6) * 16 + (e & 15);
    const int wr = g * 2048 + j;
    const int col = threadIdx.x * 4;   // 0..1020
    float4 v;
    if (seg == 0)
        v = *reinterpret_cast<const float4*>(Wih + (size_t)wr * 1024 + col);
    else
        v = *reinterpret_cast<const float4*>(Whh + (size_t)wr * 2048 + (seg - 1) * 1024 + col);
    uint2 p = make_uint2((u32)f2bf(v.x) | ((u32)f2bf(v.y) << 16),
                         (u32)f2bf(v.z) | ((u32)f2bf(v.w) << 16));
    *reinterpret_cast<uint2*>(Wcat + (size_t)e * 3072 + seg * 1024 + col) = p;
}

// Scatter emb rows into each level's Xcat slab (x-part).
__global__ void conv_emb_cat(const float* __restrict__ emb, u16* __restrict__ Xcat) {
    const int r = blockIdx.x;                 // 0..4094 (node id)
    const int k = 31 - __builtin_clz(r + 1);  // level
    const int m = (r + 1) - (1 << k);
    const size_t drow = (size_t)(4096 - (2 << k) + m);
    const int col = threadIdx.x * 4;
    float4 v = *reinterpret_cast<const float4*>(emb + (size_t)r * 1024 + col);
    uint2 p = make_uint2((u32)f2bf(v.x) | ((u32)f2bf(v.y) << 16),
                         (u32)f2bf(v.z) | ((u32)f2bf(v.w) << 16));
    *reinterpret_cast<uint2*>(Xcat + drow * 3072 + col) = p;
}

// ---------------------------------------------------------------- fused level
template <int MI, int MW, int NW, int KG>
__global__ __launch_bounds__(MW* NW* KG * 64) void fused_level(
    const u16* __restrict__ A,       // level slab: n rows x 3072
    const u16* __restrict__ Wc,      // Wcat 4096 x 3072
    const float* __restrict__ bg,    // 4096
    const float* __restrict__ cprev, // compact c or null
    u16* __restrict__ hnext,         // next slab h-base + 1024 (or null)
    float* __restrict__ cnext,       // compact c out
    float* __restrict__ outp,        // null unless n==1
    int n, int Ktot)
{
    constexpr int BM = MI * 16 * MW;
    constexpr int BN = NW * 64;
    constexpr int S = MW * NW;            // compute waves per kg
    constexpr int NFR = MI * 4;
    constexpr int RC = NFR > 8 ? 8 : NFR;
    constexpr int NP = NFR / RC;
    constexpr int ROWS = BM + BN;
    constexpr int SLOTS = ROWS * 4;       // gload16 slots per kg per step
    constexpr int GT = S * 64;            // threads per kg group
    constexpr int NL = SLOTS / GT;        // gloads per thread per step
    static_assert(SLOTS % GT == 0, "slot mapping must be exact");
    constexpr int STG = 2 * KG * ROWS * 64;                      // bytes
    constexpr int REDB = (KG > 1) ? (KG - 1) * S * RC * 64 * 16 : 0;
    constexpr int SMEM = STG > REDB ? STG : REDB;
    __shared__ __align__(16) char smem[SMEM];

    // block decomposition with stable XCD<->weight-tile affinity
    const int gx = gridDim.x;
    int b = blockIdx.x + gx * blockIdx.y;
    const int x = b & 7;
    int t = b >> 3;
    int ct, mt;
    if constexpr (NW == 2) {        // gy = 32 c-tiles of 128
        ct = (t & 3) * 8 + x; mt = t >> 2;
    } else {                        // gy = 64 c-tiles of 64; keep 128-row tiles on same XCD
        const int lo = t & 1; t >>= 1;
        ct = ((t & 3) * 8 + x) * 2 + lo; mt = t >> 2;
    }
    const int m0 = mt * BM;
    const int c0 = ct * BN;

    const int tid = threadIdx.x;
    const int lane = tid & 63;
    const int w = tid >> 6;
    const int kg = w / S;
    const int slot = w % S;
    const int wm = slot / NW;
    const int wn = slot % NW;

    const int Kc = Ktot / KG;
    const int kbeg = kg * Kc;
    const int nsteps = Kc / 32;     // always even for our configs

    u16* buf0 = (u16*)smem + (size_t)kg * ROWS * 32;
    u16* buf1 = (u16*)smem + (size_t)(KG + kg) * ROWS * 32;

    // staging pointers: NL slots for this thread (slot s: row s>>2, k (s&3)*8)
    const int gtid = slot * 64 + lane;
    const u16* gp[NL];
    u16* d0[NL];
    u16* d1[NL];
    #pragma unroll
    for (int i = 0; i < NL; ++i) {
        const int s = gtid + i * GT;
        const int row = s >> 2;
        const int kof = (s & 3) * 8;
        if (row < BM) {
            int ar = m0 + row;
            if (ar >= n) ar = n - 1;
            gp[i] = A + (size_t)ar * 3072 + kbeg + kof;
        } else {
            gp[i] = Wc + (size_t)(c0 + row - BM) * 3072 + kbeg + kof;
        }
        d0[i] = buf0 + s * 8;
        d1[i] = buf1 + s * 8;
    }

    f32x4 acc[MI][4];
    #pragma unroll
    for (int mi = 0; mi < MI; ++mi)
        #pragma unroll
        for (int f = 0; f < 4; ++f)
            acc[mi][f] = f32x4{0.f, 0.f, 0.f, 0.f};

    const int fl = lane & 15;
    const int kb = (lane >> 4) * 8;
    const int ar0 = wm * MI * 16;
    const int bc0 = BM + wn * 64;

    #define STAGE(dd)                                                    \
        _Pragma("unroll")                                                \
        for (int i = 0; i < NL; ++i) { gload16(gp[i], dd[i]); gp[i] += 32; }

    #define COMPUTE(bb)                                                  \
        {                                                                \
            bf16x8 a_[MI], b_[4];                                        \
            _Pragma("unroll")                                            \
            for (int mi = 0; mi < MI; ++mi)                              \
                a_[mi] = *reinterpret_cast<const bf16x8*>(                \
                    bb + (ar0 + mi * 16 + fl) * 32 + kb);                \
            _Pragma("unroll")                                            \
            for (int f = 0; f < 4; ++f)                                  \
                b_[f] = *reinterpret_cast<const bf16x8*>(                 \
                    bb + (bc0 + f * 16 + fl) * 32 + kb);                 \
            _Pragma("unroll")                                            \
            for (int mi = 0; mi < MI; ++mi)                              \
                _Pragma("unroll")                                        \
                for (int f = 0; f < 4; ++f)                              \
                    acc[mi][f] = __builtin_amdgcn_mfma_f32_16x16x32_bf16( \
                        a_[mi], b_[f], acc[mi][f], 0, 0, 0);             \
        }

    // prologue: stage step 0 into buf0
    STAGE(d0);
    for (int it = 0; it < nsteps / 2; ++it) {
        // even step: prefetch odd step into buf1, compute buf0
        if (2 * it + 1 < nsteps) { STAGE(d1); vmwait<NL>(); }
        else                     { vmwait<0>(); }
        barrier_pinned();
        COMPUTE(buf0);
        barrier_pinned();
        // odd step: prefetch next even step into buf0, compute buf1
        if (2 * it + 2 < nsteps) { STAGE(d0); vmwait<NL>(); }
        else                     { vmwait<0>(); }
        barrier_pinned();
        COMPUTE(buf1);
        barrier_pinned();
    }
    #undef STAGE
    #undef COMPUTE

    // -------- cross-K-group reduction (reuse smem)
    if constexpr (KG > 1) {
        f32x4* red = reinterpret_cast<f32x4*>(smem);
        #pragma unroll
        for (int pass = 0; pass < NP; ++pass) {
            if (kg > 0) {
                #pragma unroll
                for (int f = 0; f < RC; ++f) {
                    const int fr = pass * RC + f;
                    red[(((kg - 1) * S + slot) * RC + f) * 64 + lane] =
                        acc[fr >> 2][fr & 3];
                }
            }
            __syncthreads();
            if (kg == 0) {
                #pragma unroll
                for (int q = 1; q < KG; ++q)
                    #pragma unroll
                    for (int f = 0; f < RC; ++f) {
                        const int fr = pass * RC + f;
                        f32x4 v = red[(((q - 1) * S + slot) * RC + f) * 64 + lane];
                        acc[fr >> 2][fr & 3][0] += v[0];
                        acc[fr >> 2][fr & 3][1] += v[1];
                        acc[fr >> 2][fr & 3][2] += v[2];
                        acc[fr >> 2][fr & 3][3] += v[3];
                    }
            }
            __syncthreads();
        }
    }

    // -------- LSTM cell epilogue (kg == 0 waves only; no barriers below)
    if (kg != 0) return;
    const int j = ((c0 + wn * 64) >> 6) * 16 + fl;
    const float bi = bg[j], bf_ = bg[1024 + j];
    const float bgg = bg[2048 + j], bo = bg[3072 + j];
    #pragma unroll
    for (int mi = 0; mi < MI; ++mi) {
        #pragma unroll
        for (int r = 0; r < 4; ++r) {
            const int m = m0 + wm * MI * 16 + mi * 16 + (lane >> 4) * 4 + r;
            if (m >= n) continue;
            const float i_ = acc[mi][0][r] + bi;
            const float f_ = acc[mi][1][r] + bf_;
            const float g_ = acc[mi][2][r] + bgg;
            const float o_ = acc[mi][3][r] + bo;
            const float cc = cprev ? cprev[(size_t)m * 1024 + j] : 0.f;
            const float si = 1.0f / (1.0f + expf(-i_));
            const float sf = 1.0f / (1.0f + expf(-f_));
            const float so = 1.0f / (1.0f + expf(-o_));
            const float cn = sf * cc + si * tanhf(g_);
            const float hn = so * tanhf(cn);
            if (hnext)
                hnext[(size_t)(m >> 1) * 3072 + (m & 1) * 1024 + j] = f2bf(hn);
            if (!(m & 1))
                cnext[(size_t)(m >> 1) * 1024 + j] = cn;
            if (outp) { outp[j] = hn; outp[1024 + j] = cn; }
        }
    }
}

// ---------------------------------------------------------------- launcher
extern "C" void kernel_launch(void* const* d_in, const int* in_sizes, int n_in,
                              void* d_out, int out_size, void* d_ws, size_t ws_size,
                              hipStream_t stream) {
    const float* emb  = (const float*)d_in[0];
    const float* W_ih = (const float*)d_in[1];
    const float* W_hh = (const float*)d_in[2];
    const float* b_ih = (const float*)d_in[3];
    const float* b_hh = (const float*)d_in[4];
    float* out = (float*)d_out;

    char* p = (char*)d_ws;
    float* bg  = (float*)p;  p += 16384;
    u16* Wcat  = (u16*)p;    p += (size_t)4096 * 3072 * 2;   // 25.2 MB
    u16* Xcat  = (u16*)p;    p += (size_t)4096 * 3072 * 2;   // 25.2 MB
    float* cbA = (float*)p;  p += (size_t)1024 * 1024 * 4;   //  4.2 MB
    float* cbB = (float*)p;  p += (size_t)1024 * 1024 * 4;   //  4.2 MB

    bias_kernel<<<16, 256, 0, stream>>>(b_ih, b_hh, bg);
    pack_w<<<dim3(4096, 3), 256, 0, stream>>>(W_ih, W_hh, Wcat);
    conv_emb_cat<<<4095, 256, 0, stream>>>(emb, Xcat);

    #define OFF(k) (4096 - (2 << (k)))

    // level 11: K=1024 (h=c=0 skipped), h -> level-10 slab, c -> cbA.
    fused_level<4, 1, 2, 2><<<dim3(32, 32), 256, 0, stream>>>(
        Xcat, Wcat, bg, nullptr,
        Xcat + (size_t)OFF(10) * 3072 + 1024, cbA, nullptr, 2048, 1024);

    const float* cprev = cbA;
    float* cbufs[2] = {cbB, cbA};
    int t = 0;
    for (int k = TREE_DEPTH - 2; k >= 0; --k) {
        const int n = 1 << k;
        const u16* A = Xcat + (size_t)OFF(k) * 3072;
        u16* hnext = (k > 0) ? (Xcat + (size_t)OFF(k - 1) * 3072 + 1024) : nullptr;
        float* cnext = cbufs[t];
        float* outp = (k == 0) ? out : nullptr;

        if (k >= 10) {         // n=1024: BM=64, 512 blocks
            fused_level<4, 1, 2, 2><<<dim3(16, 32), 256, 0, stream>>>(
                A, Wcat, bg, cprev, hnext, cnext, outp, n, 3072);
        } else if (k >= 8) {   // n=512/256: BM=32, 512/256 blocks
            dim3 grid(n / 32, 32);
            fused_level<2, 1, 2, 2><<<grid, 256, 0, stream>>>(
                A, Wcat, bg, cprev, hnext, cnext, outp, n, 3072);
        } else {               // n<=128: BM=16, BN=64, KG=8
            dim3 grid(n >= 16 ? n / 16 : 1, 64);
            fused_level<1, 1, 1, 8><<<grid, 512, 0, stream>>>(
                A, Wcat, bg, cprev, hnext, cnext, outp, n, 3072);
        }
        cprev = cnext; t ^= 1;
    }
}